// Round 3
// baseline (100.818 us; speedup 1.0000x reference)
//
#include <hip/hip_runtime.h>

// Loss = weighted-BCE(score)/m + Huber(geometry)/(8*n_pix), single fused pass.
// beta = 1 - sum(Y_true_score)/N factors out: S0=sum(yt), S1=sum(yt*log(yp)),
// S2=sum((1-yt)*log(1-yp)), SG=sum(huber); a last-block finalize combines.
//
// Round-3 changes vs round-2 (31.7us):
//  - single kernel: per-block partials + threadfence + atomic-counter
//    last-block finalize (removes 2nd launch + tiny-kernel exec, ~3-4us)
//  - geometry: 8-deep load batches (16 dwordx4 in flight/wave); for the
//    reference shape each thread's geometry work is exactly one batch
//  - counter zeroed per call by a 4-byte hipMemsetAsync node (capture-safe)

#define THREADS 256
#define MAXNB 2048

__device__ __forceinline__ float huber4(float4 t, float4 p) {
    float dx = fabsf(t.x - p.x);
    float dy = fabsf(t.y - p.y);
    float dz = fabsf(t.z - p.z);
    float dw = fabsf(t.w - p.w);
    float hx = (dx < 1.f) ? 0.5f * dx * dx : dx - 0.5f;
    float hy = (dy < 1.f) ? 0.5f * dy * dy : dy - 0.5f;
    float hz = (dz < 1.f) ? 0.5f * dz * dz : dz - 0.5f;
    float hw = (dw < 1.f) ? 0.5f * dw * dw : dw - 0.5f;
    return (hx + hy) + (hz + hw);
}

__global__ __launch_bounds__(THREADS, 4) void
loss_fused(const float4* __restrict__ yts,
           const float4* __restrict__ yps,
           const float4* __restrict__ ytg,
           const float4* __restrict__ ypg,
           float4* __restrict__ partial,
           unsigned* __restrict__ cnt,
           float* __restrict__ out,
           int n_s4, int n_g4,
           float inv_n_score, float inv_m, float inv_geo_div) {
    const int tid = blockIdx.x * THREADS + threadIdx.x;
    const int T   = gridDim.x * THREADS;

    float s0 = 0.f, s1 = 0.f, s2 = 0.f, sg = 0.f;

    // --- score arrays: BCE partial sums (1/9 of traffic) ---
    for (int i = tid; i < n_s4; i += T) {
        float4 t = yts[i];
        float4 p = yps[i];
        s0 += (t.x + t.y) + (t.z + t.w);
        s1 += t.x * __logf(p.x) + t.y * __logf(p.y)
            + t.z * __logf(p.z) + t.w * __logf(p.w);
        s2 += (1.f - t.x) * __logf(1.f - p.x) + (1.f - t.y) * __logf(1.f - p.y)
            + (1.f - t.z) * __logf(1.f - p.z) + (1.f - t.w) * __logf(1.f - p.w);
    }

    // --- geometry: Huber, 8-deep load batches (16 loads in flight) ---
    int i = tid;
    for (; i + 7 * T < n_g4; i += 8 * T) {
        float4 t0 = ytg[i];         float4 p0 = ypg[i];
        float4 t1 = ytg[i + T];     float4 p1 = ypg[i + T];
        float4 t2 = ytg[i + 2 * T]; float4 p2 = ypg[i + 2 * T];
        float4 t3 = ytg[i + 3 * T]; float4 p3 = ypg[i + 3 * T];
        float4 t4 = ytg[i + 4 * T]; float4 p4 = ypg[i + 4 * T];
        float4 t5 = ytg[i + 5 * T]; float4 p5 = ypg[i + 5 * T];
        float4 t6 = ytg[i + 6 * T]; float4 p6 = ypg[i + 6 * T];
        float4 t7 = ytg[i + 7 * T]; float4 p7 = ypg[i + 7 * T];
        sg += huber4(t0, p0);
        sg += huber4(t1, p1);
        sg += huber4(t2, p2);
        sg += huber4(t3, p3);
        sg += huber4(t4, p4);
        sg += huber4(t5, p5);
        sg += huber4(t6, p6);
        sg += huber4(t7, p7);
    }
    for (; i < n_g4; i += T) {  // tail (empty for reference shape)
        sg += huber4(ytg[i], ypg[i]);
    }

    // --- wave (64-lane) butterfly reduce ---
    #pragma unroll
    for (int off = 32; off > 0; off >>= 1) {
        s0 += __shfl_down(s0, off);
        s1 += __shfl_down(s1, off);
        s2 += __shfl_down(s2, off);
        sg += __shfl_down(sg, off);
    }

    // --- cross-wave reduce in LDS ---
    __shared__ float lds[4][4];
    __shared__ int is_last;
    const int wave = threadIdx.x >> 6;
    const int lane = threadIdx.x & 63;
    if (lane == 0) {
        lds[wave][0] = s0; lds[wave][1] = s1;
        lds[wave][2] = s2; lds[wave][3] = sg;
    }
    __syncthreads();
    if (threadIdx.x == 0) {
        float4 r;
        r.x = lds[0][0] + lds[1][0] + lds[2][0] + lds[3][0];
        r.y = lds[0][1] + lds[1][1] + lds[2][1] + lds[3][1];
        r.z = lds[0][2] + lds[1][2] + lds[2][2] + lds[3][2];
        r.w = lds[0][3] + lds[1][3] + lds[2][3] + lds[3][3];
        partial[blockIdx.x] = r;
        __threadfence();                       // device-scope release of partial
        unsigned old = atomicAdd(cnt, 1u);     // device-scope by default
        is_last = (old == (unsigned)(gridDim.x - 1)) ? 1 : 0;
    }
    __syncthreads();

    // --- last block finalizes ---
    if (is_last) {
        __threadfence();                       // invalidate local caches -> fresh partials
        float a0 = 0.f, a1 = 0.f, a2 = 0.f, a3 = 0.f;
        for (int j = threadIdx.x; j < (int)gridDim.x; j += THREADS) {
            float4 v = partial[j];
            a0 += v.x; a1 += v.y; a2 += v.z; a3 += v.w;
        }
        #pragma unroll
        for (int off = 32; off > 0; off >>= 1) {
            a0 += __shfl_down(a0, off);
            a1 += __shfl_down(a1, off);
            a2 += __shfl_down(a2, off);
            a3 += __shfl_down(a3, off);
        }
        __syncthreads();                       // lds[][] reuse is safe after this
        if (lane == 0) {
            lds[wave][0] = a0; lds[wave][1] = a1;
            lds[wave][2] = a2; lds[wave][3] = a3;
        }
        __syncthreads();
        if (threadIdx.x == 0) {
            const float S0 = lds[0][0] + lds[1][0] + lds[2][0] + lds[3][0];
            const float S1 = lds[0][1] + lds[1][1] + lds[2][1] + lds[3][1];
            const float S2 = lds[0][2] + lds[1][2] + lds[2][2] + lds[3][2];
            const float SG = lds[0][3] + lds[1][3] + lds[2][3] + lds[3][3];
            const float beta = 1.f - S0 * inv_n_score;
            const float loss_score = (-beta * S1 - (1.f - beta) * S2) * inv_m;
            const float loss_geo   = SG * inv_geo_div;  // LAMBDA_GEOMETRY = 1
            out[0] = loss_score + loss_geo;
        }
    }
}

extern "C" void kernel_launch(void* const* d_in, const int* in_sizes, int n_in,
                              void* d_out, int out_size, void* d_ws, size_t ws_size,
                              hipStream_t stream) {
    const float4* yts = (const float4*)d_in[0];
    const float4* yps = (const float4*)d_in[1];
    const float4* ytg = (const float4*)d_in[2];
    const float4* ypg = (const float4*)d_in[3];
    float* out = (float*)d_out;

    const int n_score = in_sizes[0];          // m*1*H*W = 2,097,152
    const int n_geo   = in_sizes[2];          // m*8*H*W = 16,777,216
    const int n_s4 = n_score / 4;
    const int n_g4 = n_geo / 4;

    int blocks = MAXNB;
    const size_t need = (size_t)blocks * sizeof(float4) + sizeof(unsigned);
    if (ws_size < need)
        blocks = (int)((ws_size - sizeof(unsigned)) / sizeof(float4));

    float4* partial = (float4*)d_ws;
    unsigned* cnt = (unsigned*)((char*)d_ws + (size_t)blocks * sizeof(float4));

    // m=128 per reference; n_pix = m*H*W = n_score; divisor = 8 * n_score
    const float inv_n_score = 1.f / (float)n_score;
    const float inv_m       = 1.f / 128.f;
    const float inv_geo_div = 1.f / (8.f * (float)n_score);

    // counter must be 0 at kernel start each call (d_ws not re-poisoned)
    hipMemsetAsync(cnt, 0, sizeof(unsigned), stream);

    loss_fused<<<blocks, THREADS, 0, stream>>>(yts, yps, ytg, ypg,
                                               partial, cnt, out,
                                               n_s4, n_g4,
                                               inv_n_score, inv_m, inv_geo_div);
}

// Round 4
// 99.225 us; speedup vs baseline: 1.0161x; 1.0161x over previous
//
#include <hip/hip_runtime.h>

// Loss = weighted-BCE(score)/m + Huber(geometry)/(8*n_pix), single fused pass.
// beta = 1 - sum(Y_true_score)/N factors out: S0=sum(yt), S1=sum(yt*log(yp)),
// S2=sum((1-yt)*log(1-yp)), SG=sum(huber); last-block finalize combines.
//
// Round-4: round-2's main loop EXACTLY (4-deep batches, 31.7us known-good;
// round-3's 8-deep rewrite serialized loads and regressed 3x) + fused
// last-block finalize to remove the 2nd launch. Only the tail differs
// from round 2.

#define THREADS 256
#define MAXNB 2048

__global__ __launch_bounds__(THREADS) void
loss_fused(const float4* __restrict__ yts,
           const float4* __restrict__ yps,
           const float4* __restrict__ ytg,
           const float4* __restrict__ ypg,
           float4* __restrict__ partial,
           unsigned* __restrict__ cnt,
           float* __restrict__ out,
           int n_s4, int n_g4,
           float inv_n_score, float inv_m, float inv_geo_div) {
    const int tid = blockIdx.x * THREADS + threadIdx.x;
    const int T   = gridDim.x * THREADS;

    float s0 = 0.f, s1 = 0.f, s2 = 0.f, sg = 0.f;

    // --- score arrays: BCE partial sums (1/9 of traffic) ---
    for (int i = tid; i < n_s4; i += T) {
        float4 t = yts[i];
        float4 p = yps[i];
        s0 += (t.x + t.y) + (t.z + t.w);
        s1 += t.x * __logf(p.x) + t.y * __logf(p.y)
            + t.z * __logf(p.z) + t.w * __logf(p.w);
        s2 += (1.f - t.x) * __logf(1.f - p.x) + (1.f - t.y) * __logf(1.f - p.y)
            + (1.f - t.z) * __logf(1.f - p.z) + (1.f - t.w) * __logf(1.f - p.w);
    }

    // --- geometry arrays: Huber, 4-deep load batches (round-2 exact) ---
    int i = tid;
    for (; i + 3 * T < n_g4; i += 4 * T) {
        // issue all 8 loads before consuming any
        float4 t0 = ytg[i];
        float4 t1 = ytg[i + T];
        float4 t2 = ytg[i + 2 * T];
        float4 t3 = ytg[i + 3 * T];
        float4 p0 = ypg[i];
        float4 p1 = ypg[i + T];
        float4 p2 = ypg[i + 2 * T];
        float4 p3 = ypg[i + 3 * T];

        #pragma unroll
        for (int k = 0; k < 4; ++k) {
            float4 t = (k == 0) ? t0 : (k == 1) ? t1 : (k == 2) ? t2 : t3;
            float4 p = (k == 0) ? p0 : (k == 1) ? p1 : (k == 2) ? p2 : p3;
            float dx = fabsf(t.x - p.x);
            float dy = fabsf(t.y - p.y);
            float dz = fabsf(t.z - p.z);
            float dw = fabsf(t.w - p.w);
            float hx = (dx < 1.f) ? 0.5f * dx * dx : dx - 0.5f;
            float hy = (dy < 1.f) ? 0.5f * dy * dy : dy - 0.5f;
            float hz = (dz < 1.f) ? 0.5f * dz * dz : dz - 0.5f;
            float hw = (dw < 1.f) ? 0.5f * dw * dw : dw - 0.5f;
            sg += (hx + hy) + (hz + hw);
        }
    }
    for (; i < n_g4; i += T) {  // tail (empty for the reference shape)
        float4 t = ytg[i];
        float4 p = ypg[i];
        float dx = fabsf(t.x - p.x);
        float dy = fabsf(t.y - p.y);
        float dz = fabsf(t.z - p.z);
        float dw = fabsf(t.w - p.w);
        float hx = (dx < 1.f) ? 0.5f * dx * dx : dx - 0.5f;
        float hy = (dy < 1.f) ? 0.5f * dy * dy : dy - 0.5f;
        float hz = (dz < 1.f) ? 0.5f * dz * dz : dz - 0.5f;
        float hw = (dw < 1.f) ? 0.5f * dw * dw : dw - 0.5f;
        sg += (hx + hy) + (hz + hw);
    }

    // --- wave (64-lane) butterfly reduce ---
    #pragma unroll
    for (int off = 32; off > 0; off >>= 1) {
        s0 += __shfl_down(s0, off);
        s1 += __shfl_down(s1, off);
        s2 += __shfl_down(s2, off);
        sg += __shfl_down(sg, off);
    }

    // --- cross-wave reduce in LDS, one float4 store per block ---
    __shared__ float lds[4][4];
    __shared__ int is_last;
    const int wave = threadIdx.x >> 6;
    const int lane = threadIdx.x & 63;
    if (lane == 0) {
        lds[wave][0] = s0; lds[wave][1] = s1;
        lds[wave][2] = s2; lds[wave][3] = sg;
    }
    __syncthreads();
    if (threadIdx.x == 0) {
        float4 r;
        r.x = lds[0][0] + lds[1][0] + lds[2][0] + lds[3][0];
        r.y = lds[0][1] + lds[1][1] + lds[2][1] + lds[3][1];
        r.z = lds[0][2] + lds[1][2] + lds[2][2] + lds[3][2];
        r.w = lds[0][3] + lds[1][3] + lds[2][3] + lds[3][3];
        partial[blockIdx.x] = r;
        __threadfence();                    // device-scope release of partial
        unsigned old = atomicAdd(cnt, 1u);  // device-scope by default
        is_last = (old == (unsigned)(gridDim.x - 1)) ? 1 : 0;
    }
    __syncthreads();

    // --- last block finalizes (reads all partials, writes out[0]) ---
    if (is_last) {
        __threadfence();  // acquire: see other blocks' partial stores
        float a0 = 0.f, a1 = 0.f, a2 = 0.f, a3 = 0.f;
        for (int j = threadIdx.x; j < (int)gridDim.x; j += THREADS) {
            float4 v = partial[j];
            a0 += v.x; a1 += v.y; a2 += v.z; a3 += v.w;
        }
        #pragma unroll
        for (int off = 32; off > 0; off >>= 1) {
            a0 += __shfl_down(a0, off);
            a1 += __shfl_down(a1, off);
            a2 += __shfl_down(a2, off);
            a3 += __shfl_down(a3, off);
        }
        __syncthreads();
        if (lane == 0) {
            lds[wave][0] = a0; lds[wave][1] = a1;
            lds[wave][2] = a2; lds[wave][3] = a3;
        }
        __syncthreads();
        if (threadIdx.x == 0) {
            const float S0 = lds[0][0] + lds[1][0] + lds[2][0] + lds[3][0];
            const float S1 = lds[0][1] + lds[1][1] + lds[2][1] + lds[3][1];
            const float S2 = lds[0][2] + lds[1][2] + lds[2][2] + lds[3][2];
            const float SG = lds[0][3] + lds[1][3] + lds[2][3] + lds[3][3];
            const float beta = 1.f - S0 * inv_n_score;
            const float loss_score = (-beta * S1 - (1.f - beta) * S2) * inv_m;
            const float loss_geo   = SG * inv_geo_div;  // LAMBDA_GEOMETRY = 1
            out[0] = loss_score + loss_geo;
        }
    }
}

extern "C" void kernel_launch(void* const* d_in, const int* in_sizes, int n_in,
                              void* d_out, int out_size, void* d_ws, size_t ws_size,
                              hipStream_t stream) {
    const float4* yts = (const float4*)d_in[0];
    const float4* yps = (const float4*)d_in[1];
    const float4* ytg = (const float4*)d_in[2];
    const float4* ypg = (const float4*)d_in[3];
    float* out = (float*)d_out;

    const int n_score = in_sizes[0];          // m*1*H*W = 2,097,152
    const int n_geo   = in_sizes[2];          // m*8*H*W = 16,777,216
    const int n_s4 = n_score / 4;
    const int n_g4 = n_geo / 4;

    int blocks = MAXNB;
    const size_t need = (size_t)blocks * sizeof(float4) + sizeof(unsigned);
    if (ws_size < need)
        blocks = (int)((ws_size - sizeof(unsigned)) / sizeof(float4));

    float4* partial = (float4*)d_ws;
    unsigned* cnt = (unsigned*)((char*)d_ws + (size_t)blocks * sizeof(float4));

    // m=128 per reference; n_pix = m*H*W = n_score; divisor = 8 * n_score
    const float inv_n_score = 1.f / (float)n_score;
    const float inv_m       = 1.f / 128.f;
    const float inv_geo_div = 1.f / (8.f * (float)n_score);

    // counter must be 0 at kernel start each call (d_ws not re-poisoned)
    hipMemsetAsync(cnt, 0, sizeof(unsigned), stream);

    loss_fused<<<blocks, THREADS, 0, stream>>>(yts, yps, ytg, ypg,
                                               partial, cnt, out,
                                               n_s4, n_g4,
                                               inv_n_score, inv_m, inv_geo_div);
}

// Round 5
// 34.806 us; speedup vs baseline: 2.8966x; 2.8508x over previous
//
#include <hip/hip_runtime.h>

// Loss = weighted-BCE(score)/m + Huber(geometry)/(8*n_pix), single fused pass.
// beta = 1 - sum(Y_true_score)/N factors out: S0=sum(yt), S1=sum(yt*log(yp)),
// S2=sum((1-yt)*log(1-yp)), SG=sum(huber); finalize combines.
//
// Round-5: EXACT revert to round-2 (31.7us known-good).
// Evidence from R1/R3/R4: any kernel with device-scope atomics/threadfence
// in the tail runs ~150us (L2 writeback per block + same-line atomic
// serialization across XCDs); the atomic-free two-kernel version runs 50us
// (profiled) / 31.7us (bench). R4 proved the main loop was byte-identical,
// so the tail is causal. Do NOT fuse via atomics on this chip.

#define THREADS 256

__global__ __launch_bounds__(THREADS) void
loss_reduce(const float4* __restrict__ yts,
            const float4* __restrict__ yps,
            const float4* __restrict__ ytg,
            const float4* __restrict__ ypg,
            float4* __restrict__ partial,
            int n_s4, int n_g4) {
    const int tid = blockIdx.x * THREADS + threadIdx.x;
    const int T   = gridDim.x * THREADS;

    float s0 = 0.f, s1 = 0.f, s2 = 0.f, sg = 0.f;

    // --- score arrays: BCE partial sums (1/9 of traffic) ---
    for (int i = tid; i < n_s4; i += T) {
        float4 t = yts[i];
        float4 p = yps[i];
        s0 += (t.x + t.y) + (t.z + t.w);
        s1 += t.x * __logf(p.x) + t.y * __logf(p.y)
            + t.z * __logf(p.z) + t.w * __logf(p.w);
        s2 += (1.f - t.x) * __logf(1.f - p.x) + (1.f - t.y) * __logf(1.f - p.y)
            + (1.f - t.z) * __logf(1.f - p.z) + (1.f - t.w) * __logf(1.f - p.w);
    }

    // --- geometry arrays: Huber, 4-deep load batches for MLP ---
    int i = tid;
    for (; i + 3 * T < n_g4; i += 4 * T) {
        // issue all 8 loads before consuming any
        float4 t0 = ytg[i];
        float4 t1 = ytg[i + T];
        float4 t2 = ytg[i + 2 * T];
        float4 t3 = ytg[i + 3 * T];
        float4 p0 = ypg[i];
        float4 p1 = ypg[i + T];
        float4 p2 = ypg[i + 2 * T];
        float4 p3 = ypg[i + 3 * T];

        #pragma unroll
        for (int k = 0; k < 4; ++k) {
            float4 t = (k == 0) ? t0 : (k == 1) ? t1 : (k == 2) ? t2 : t3;
            float4 p = (k == 0) ? p0 : (k == 1) ? p1 : (k == 2) ? p2 : p3;
            float dx = fabsf(t.x - p.x);
            float dy = fabsf(t.y - p.y);
            float dz = fabsf(t.z - p.z);
            float dw = fabsf(t.w - p.w);
            float hx = (dx < 1.f) ? 0.5f * dx * dx : dx - 0.5f;
            float hy = (dy < 1.f) ? 0.5f * dy * dy : dy - 0.5f;
            float hz = (dz < 1.f) ? 0.5f * dz * dz : dz - 0.5f;
            float hw = (dw < 1.f) ? 0.5f * dw * dw : dw - 0.5f;
            sg += (hx + hy) + (hz + hw);
        }
    }
    for (; i < n_g4; i += T) {  // tail (empty for the reference shape)
        float4 t = ytg[i];
        float4 p = ypg[i];
        float dx = fabsf(t.x - p.x);
        float dy = fabsf(t.y - p.y);
        float dz = fabsf(t.z - p.z);
        float dw = fabsf(t.w - p.w);
        float hx = (dx < 1.f) ? 0.5f * dx * dx : dx - 0.5f;
        float hy = (dy < 1.f) ? 0.5f * dy * dy : dy - 0.5f;
        float hz = (dz < 1.f) ? 0.5f * dz * dz : dz - 0.5f;
        float hw = (dw < 1.f) ? 0.5f * dw * dw : dw - 0.5f;
        sg += (hx + hy) + (hz + hw);
    }

    // --- wave (64-lane) butterfly reduce ---
    #pragma unroll
    for (int off = 32; off > 0; off >>= 1) {
        s0 += __shfl_down(s0, off);
        s1 += __shfl_down(s1, off);
        s2 += __shfl_down(s2, off);
        sg += __shfl_down(sg, off);
    }

    // --- cross-wave reduce in LDS, one float4 store per block ---
    __shared__ float lds[4][4];
    const int wave = threadIdx.x >> 6;
    const int lane = threadIdx.x & 63;
    if (lane == 0) {
        lds[wave][0] = s0; lds[wave][1] = s1;
        lds[wave][2] = s2; lds[wave][3] = sg;
    }
    __syncthreads();
    if (threadIdx.x == 0) {
        float4 r;
        r.x = lds[0][0] + lds[1][0] + lds[2][0] + lds[3][0];
        r.y = lds[0][1] + lds[1][1] + lds[2][1] + lds[3][1];
        r.z = lds[0][2] + lds[1][2] + lds[2][2] + lds[3][2];
        r.w = lds[0][3] + lds[1][3] + lds[2][3] + lds[3][3];
        partial[blockIdx.x] = r;
    }
}

__global__ __launch_bounds__(THREADS) void
loss_finalize(const float4* __restrict__ partial, int nblocks,
              float* __restrict__ out,
              float inv_n_score, float inv_m, float inv_geo_div) {
    float s0 = 0.f, s1 = 0.f, s2 = 0.f, sg = 0.f;
    for (int i = threadIdx.x; i < nblocks; i += THREADS) {
        float4 v = partial[i];
        s0 += v.x; s1 += v.y; s2 += v.z; sg += v.w;
    }
    #pragma unroll
    for (int off = 32; off > 0; off >>= 1) {
        s0 += __shfl_down(s0, off);
        s1 += __shfl_down(s1, off);
        s2 += __shfl_down(s2, off);
        sg += __shfl_down(sg, off);
    }
    __shared__ float lds[4][4];
    const int wave = threadIdx.x >> 6;
    const int lane = threadIdx.x & 63;
    if (lane == 0) {
        lds[wave][0] = s0; lds[wave][1] = s1;
        lds[wave][2] = s2; lds[wave][3] = sg;
    }
    __syncthreads();
    if (threadIdx.x == 0) {
        const float S0 = lds[0][0] + lds[1][0] + lds[2][0] + lds[3][0];
        const float S1 = lds[0][1] + lds[1][1] + lds[2][1] + lds[3][1];
        const float S2 = lds[0][2] + lds[1][2] + lds[2][2] + lds[3][2];
        const float SG = lds[0][3] + lds[1][3] + lds[2][3] + lds[3][3];
        const float beta = 1.f - S0 * inv_n_score;
        const float loss_score = (-beta * S1 - (1.f - beta) * S2) * inv_m;
        const float loss_geo   = SG * inv_geo_div;  // LAMBDA_GEOMETRY = 1
        out[0] = loss_score + loss_geo;
    }
}

extern "C" void kernel_launch(void* const* d_in, const int* in_sizes, int n_in,
                              void* d_out, int out_size, void* d_ws, size_t ws_size,
                              hipStream_t stream) {
    const float4* yts = (const float4*)d_in[0];
    const float4* yps = (const float4*)d_in[1];
    const float4* ytg = (const float4*)d_in[2];
    const float4* ypg = (const float4*)d_in[3];
    float* out = (float*)d_out;
    float4* partial = (float4*)d_ws;

    const int n_score = in_sizes[0];          // m*1*H*W = 2,097,152
    const int n_geo   = in_sizes[2];          // m*8*H*W = 16,777,216
    const int n_s4 = n_score / 4;
    const int n_g4 = n_geo / 4;

    int blocks = 2048;                        // 8 blocks/CU, 32 waves/CU
    const size_t need = (size_t)blocks * sizeof(float4);
    if (ws_size < need) blocks = (int)(ws_size / sizeof(float4));  // safety

    // m=128; n_pix = m*H*W = n_score; divisor = n_c * n_pix = 8 * n_score
    const float inv_n_score = 1.f / (float)n_score;
    const float inv_m       = 1.f / 128.f;
    const float inv_geo_div = 1.f / (8.f * (float)n_score);

    loss_reduce<<<blocks, THREADS, 0, stream>>>(yts, yps, ytg, ypg, partial,
                                                n_s4, n_g4);
    loss_finalize<<<1, THREADS, 0, stream>>>(partial, blocks, out,
                                             inv_n_score, inv_m, inv_geo_div);
}

// Round 6
// 31.493 us; speedup vs baseline: 3.2013x; 1.1052x over previous
//
#include <hip/hip_runtime.h>

// Loss = weighted-BCE(score)/m + Huber(geometry)/(8*n_pix), single fused pass.
// beta = 1 - sum(Y_true_score)/N factors out: S0=sum(yt), S1=sum(yt*log(yp)),
// S2=sum((1-yt)*log(1-yp)), SG=sum(huber); finalize combines.
//
// Round-6: shape-specialized straight-line reduce kernel.
// With 2048x256 threads and the reference shape, every thread does exactly
// 1 score float4 + 8 geometry float4-pairs. The generic loops (runtime trip
// counts) force 3 serialized wait points; the specialized version issues all
// 18 global_load_dwordx4 up-front in consumption order -> one latency
// exposure, score-log VALU hides under in-flight geometry loads.
// Reduction tail and finalize kernel are byte-identical to round-2/5
// (known-good; R4 proved fused atomic tails cost ~100us on this chip).
// Generic R2 kernel kept as fallback for non-reference shapes.

#define THREADS 256
#define NBLOCKS 2048

__device__ __forceinline__ float huber4(float4 t, float4 p) {
    float dx = fabsf(t.x - p.x);
    float dy = fabsf(t.y - p.y);
    float dz = fabsf(t.z - p.z);
    float dw = fabsf(t.w - p.w);
    float hx = (dx < 1.f) ? 0.5f * dx * dx : dx - 0.5f;
    float hy = (dy < 1.f) ? 0.5f * dy * dy : dy - 0.5f;
    float hz = (dz < 1.f) ? 0.5f * dz * dz : dz - 0.5f;
    float hw = (dw < 1.f) ? 0.5f * dw * dw : dw - 0.5f;
    return (hx + hy) + (hz + hw);
}

// ---- block-level reduce tail shared by both reduce kernels (R2-exact) ----
__device__ __forceinline__ void
block_reduce_store(float s0, float s1, float s2, float sg,
                   float4* __restrict__ partial) {
    #pragma unroll
    for (int off = 32; off > 0; off >>= 1) {
        s0 += __shfl_down(s0, off);
        s1 += __shfl_down(s1, off);
        s2 += __shfl_down(s2, off);
        sg += __shfl_down(sg, off);
    }
    __shared__ float lds[4][4];
    const int wave = threadIdx.x >> 6;
    const int lane = threadIdx.x & 63;
    if (lane == 0) {
        lds[wave][0] = s0; lds[wave][1] = s1;
        lds[wave][2] = s2; lds[wave][3] = sg;
    }
    __syncthreads();
    if (threadIdx.x == 0) {
        float4 r;
        r.x = lds[0][0] + lds[1][0] + lds[2][0] + lds[3][0];
        r.y = lds[0][1] + lds[1][1] + lds[2][1] + lds[3][1];
        r.z = lds[0][2] + lds[1][2] + lds[2][2] + lds[3][2];
        r.w = lds[0][3] + lds[1][3] + lds[2][3] + lds[3][3];
        partial[blockIdx.x] = r;
    }
}

// ---- specialized: n_s4 == T, n_g4 == 8*T exactly ----
__global__ __launch_bounds__(THREADS) void
loss_reduce_exact(const float4* __restrict__ yts,
                  const float4* __restrict__ yps,
                  const float4* __restrict__ ytg,
                  const float4* __restrict__ ypg,
                  float4* __restrict__ partial) {
    const int tid = blockIdx.x * THREADS + threadIdx.x;
    const int T   = gridDim.x * THREADS;

    // issue all 18 loads up-front, in consumption order
    float4 st = yts[tid];
    float4 sp = yps[tid];
    float4 t0 = ytg[tid];         float4 p0 = ypg[tid];
    float4 t1 = ytg[tid + T];     float4 p1 = ypg[tid + T];
    float4 t2 = ytg[tid + 2 * T]; float4 p2 = ypg[tid + 2 * T];
    float4 t3 = ytg[tid + 3 * T]; float4 p3 = ypg[tid + 3 * T];
    float4 t4 = ytg[tid + 4 * T]; float4 p4 = ypg[tid + 4 * T];
    float4 t5 = ytg[tid + 5 * T]; float4 p5 = ypg[tid + 5 * T];
    float4 t6 = ytg[tid + 6 * T]; float4 p6 = ypg[tid + 6 * T];
    float4 t7 = ytg[tid + 7 * T]; float4 p7 = ypg[tid + 7 * T];

    // score BCE partials (waits only on st/sp; geo loads still in flight)
    float s0 = (st.x + st.y) + (st.z + st.w);
    float s1 = st.x * __logf(sp.x) + st.y * __logf(sp.y)
             + st.z * __logf(sp.z) + st.w * __logf(sp.w);
    float s2 = (1.f - st.x) * __logf(1.f - sp.x)
             + (1.f - st.y) * __logf(1.f - sp.y)
             + (1.f - st.z) * __logf(1.f - sp.z)
             + (1.f - st.w) * __logf(1.f - sp.w);

    // geometry Huber, consumed in load-issue order
    float sg = huber4(t0, p0);
    sg += huber4(t1, p1);
    sg += huber4(t2, p2);
    sg += huber4(t3, p3);
    sg += huber4(t4, p4);
    sg += huber4(t5, p5);
    sg += huber4(t6, p6);
    sg += huber4(t7, p7);

    block_reduce_store(s0, s1, s2, sg, partial);
}

// ---- generic fallback: round-2 exact main loop ----
__global__ __launch_bounds__(THREADS) void
loss_reduce(const float4* __restrict__ yts,
            const float4* __restrict__ yps,
            const float4* __restrict__ ytg,
            const float4* __restrict__ ypg,
            float4* __restrict__ partial,
            int n_s4, int n_g4) {
    const int tid = blockIdx.x * THREADS + threadIdx.x;
    const int T   = gridDim.x * THREADS;

    float s0 = 0.f, s1 = 0.f, s2 = 0.f, sg = 0.f;

    for (int i = tid; i < n_s4; i += T) {
        float4 t = yts[i];
        float4 p = yps[i];
        s0 += (t.x + t.y) + (t.z + t.w);
        s1 += t.x * __logf(p.x) + t.y * __logf(p.y)
            + t.z * __logf(p.z) + t.w * __logf(p.w);
        s2 += (1.f - t.x) * __logf(1.f - p.x) + (1.f - t.y) * __logf(1.f - p.y)
            + (1.f - t.z) * __logf(1.f - p.z) + (1.f - t.w) * __logf(1.f - p.w);
    }

    int i = tid;
    for (; i + 3 * T < n_g4; i += 4 * T) {
        float4 t0 = ytg[i];
        float4 t1 = ytg[i + T];
        float4 t2 = ytg[i + 2 * T];
        float4 t3 = ytg[i + 3 * T];
        float4 p0 = ypg[i];
        float4 p1 = ypg[i + T];
        float4 p2 = ypg[i + 2 * T];
        float4 p3 = ypg[i + 3 * T];
        #pragma unroll
        for (int k = 0; k < 4; ++k) {
            float4 t = (k == 0) ? t0 : (k == 1) ? t1 : (k == 2) ? t2 : t3;
            float4 p = (k == 0) ? p0 : (k == 1) ? p1 : (k == 2) ? p2 : p3;
            sg += huber4(t, p);
        }
    }
    for (; i < n_g4; i += T) {
        sg += huber4(ytg[i], ypg[i]);
    }

    block_reduce_store(s0, s1, s2, sg, partial);
}

__global__ __launch_bounds__(THREADS) void
loss_finalize(const float4* __restrict__ partial, int nblocks,
              float* __restrict__ out,
              float inv_n_score, float inv_m, float inv_geo_div) {
    float s0 = 0.f, s1 = 0.f, s2 = 0.f, sg = 0.f;
    for (int i = threadIdx.x; i < nblocks; i += THREADS) {
        float4 v = partial[i];
        s0 += v.x; s1 += v.y; s2 += v.z; sg += v.w;
    }
    #pragma unroll
    for (int off = 32; off > 0; off >>= 1) {
        s0 += __shfl_down(s0, off);
        s1 += __shfl_down(s1, off);
        s2 += __shfl_down(s2, off);
        sg += __shfl_down(sg, off);
    }
    __shared__ float lds[4][4];
    const int wave = threadIdx.x >> 6;
    const int lane = threadIdx.x & 63;
    if (lane == 0) {
        lds[wave][0] = s0; lds[wave][1] = s1;
        lds[wave][2] = s2; lds[wave][3] = sg;
    }
    __syncthreads();
    if (threadIdx.x == 0) {
        const float S0 = lds[0][0] + lds[1][0] + lds[2][0] + lds[3][0];
        const float S1 = lds[0][1] + lds[1][1] + lds[2][1] + lds[3][1];
        const float S2 = lds[0][2] + lds[1][2] + lds[2][2] + lds[3][2];
        const float SG = lds[0][3] + lds[1][3] + lds[2][3] + lds[3][3];
        const float beta = 1.f - S0 * inv_n_score;
        const float loss_score = (-beta * S1 - (1.f - beta) * S2) * inv_m;
        const float loss_geo   = SG * inv_geo_div;  // LAMBDA_GEOMETRY = 1
        out[0] = loss_score + loss_geo;
    }
}

extern "C" void kernel_launch(void* const* d_in, const int* in_sizes, int n_in,
                              void* d_out, int out_size, void* d_ws, size_t ws_size,
                              hipStream_t stream) {
    const float4* yts = (const float4*)d_in[0];
    const float4* yps = (const float4*)d_in[1];
    const float4* ytg = (const float4*)d_in[2];
    const float4* ypg = (const float4*)d_in[3];
    float* out = (float*)d_out;
    float4* partial = (float4*)d_ws;

    const int n_score = in_sizes[0];          // m*1*H*W = 2,097,152
    const int n_geo   = in_sizes[2];          // m*8*H*W = 16,777,216
    const int n_s4 = n_score / 4;
    const int n_g4 = n_geo / 4;

    int blocks = NBLOCKS;
    const size_t need = (size_t)blocks * sizeof(float4);
    if (ws_size < need) blocks = (int)(ws_size / sizeof(float4));  // safety

    const int T = blocks * THREADS;

    // m=128; n_pix = m*H*W = n_score; divisor = n_c * n_pix = 8 * n_score
    const float inv_n_score = 1.f / (float)n_score;
    const float inv_m       = 1.f / 128.f;
    const float inv_geo_div = 1.f / (8.f * (float)n_score);

    if (n_s4 == T && n_g4 == 8 * T) {
        loss_reduce_exact<<<blocks, THREADS, 0, stream>>>(yts, yps, ytg, ypg,
                                                          partial);
    } else {
        loss_reduce<<<blocks, THREADS, 0, stream>>>(yts, yps, ytg, ypg, partial,
                                                    n_s4, n_g4);
    }
    loss_finalize<<<1, THREADS, 0, stream>>>(partial, blocks, out,
                                             inv_n_score, inv_m, inv_geo_div);
}